// Round 9
// baseline (225.678 us; speedup 1.0000x reference)
//
#include <hip/hip_runtime.h>

// GCN 2-layer encoder on gfx950.
// R9: software-pipelined batch-8 edge walks in both aggregates (prefetch next
// chunk's indices+rows before accumulating current chunk -> one latency
// exposure per typical walk, load issue overlaps VALU unpack/accumulate).
// Keeps R8's 2-subgroup split + shfl_xor combine (no LDS, no atomics).
// Pipeline: memset(1.5KB) -> p1_bin -> p2_csr -> gemm1(bf16 h1)
//           -> agg1_gemm2(bf16 h2) -> agg2 -> d_out (fp32).

constexpr int CAP = 8192;   // per-bucket staging cap; E/NB ~ 4092
constexpr int NBMAX = 512;  // NB = 391 for N = 100000 (must be <= 512)

__device__ inline unsigned short f2bf(float f) {  // RNE f32->bf16 (finite inputs)
    unsigned u = __float_as_uint(f);
    u += 0x7fff + ((u >> 16) & 1);
    return (unsigned short)(u >> 16);
}
__device__ inline float bflo(unsigned u) { return __uint_as_float(u << 16); }
__device__ inline float bfhi(unsigned u) { return __uint_as_float(u & 0xffff0000u); }

__device__ inline void acc8(float* acc, uint4 u) {
    acc[0] += bflo(u.x); acc[1] += bfhi(u.x);
    acc[2] += bflo(u.y); acc[3] += bfhi(u.y);
    acc[4] += bflo(u.z); acc[5] += bfhi(u.z);
    acc[6] += bflo(u.w); acc[7] += bfhi(u.w);
}

// Pipelined gather-walk: chunks of 8 with 1-deep prefetch, then 4-batch + tail.
template <int STRIDE>
__device__ inline void walk_pipe(const uint4* __restrict__ hs, const int* __restrict__ col,
                                 int q, int es, int ee, float* acc) {
    int e = es;
    if (e + 8 <= ee) {
        uint4 b[8];
        int s[8];
#pragma unroll
        for (int j = 0; j < 8; ++j) s[j] = col[e + j];
#pragma unroll
        for (int j = 0; j < 8; ++j) b[j] = hs[(size_t)s[j] * STRIDE + q];
        e += 8;
        while (e + 8 <= ee) {
            uint4 nb[8];
            int ns[8];
#pragma unroll
            for (int j = 0; j < 8; ++j) ns[j] = col[e + j];
#pragma unroll
            for (int j = 0; j < 8; ++j) nb[j] = hs[(size_t)ns[j] * STRIDE + q];
#pragma unroll
            for (int j = 0; j < 8; ++j) acc8(acc, b[j]);  // overlaps nb in flight
#pragma unroll
            for (int j = 0; j < 8; ++j) b[j] = nb[j];
            e += 8;
        }
#pragma unroll
        for (int j = 0; j < 8; ++j) acc8(acc, b[j]);
    }
    if (e + 4 <= ee) {
        int s0 = col[e], s1 = col[e + 1], s2 = col[e + 2], s3 = col[e + 3];
        uint4 b0 = hs[(size_t)s0 * STRIDE + q];
        uint4 b1 = hs[(size_t)s1 * STRIDE + q];
        uint4 b2 = hs[(size_t)s2 * STRIDE + q];
        uint4 b3 = hs[(size_t)s3 * STRIDE + q];
        acc8(acc, b0); acc8(acc, b1); acc8(acc, b2); acc8(acc, b3);
        e += 4;
    }
    for (; e < ee; ++e) acc8(acc, hs[(size_t)col[e] * STRIDE + q]);
}

__global__ __launch_bounds__(256) void p1_bin(const int* __restrict__ src,
                                              const int* __restrict__ dst,
                                              int* __restrict__ bucketCursor,
                                              unsigned* __restrict__ staging, int E, int NB) {
    __shared__ int cnt[NBMAX];
    __shared__ int cur[NBMAX];
    int tid = threadIdx.x;
    for (int i = tid; i < NB; i += 256) cnt[i] = 0;
    __syncthreads();
    int e0 = blockIdx.x * 4096;
#pragma unroll
    for (int k = 0; k < 16; ++k) {
        int e = e0 + k * 256 + tid;
        if (e < E) atomicAdd(&cnt[dst[e] >> 8], 1);  // LDS atomic
    }
    __syncthreads();
    for (int i = tid; i < NB; i += 256) {
        int c = cnt[i];
        cur[i] = c ? atomicAdd(&bucketCursor[i], c) : 0;  // 1 global atomic/(block,bucket)
    }
    __syncthreads();
#pragma unroll
    for (int k = 0; k < 16; ++k) {
        int e = e0 + k * 256 + tid;
        if (e < E) {
            int d = dst[e];
            int b = d >> 8;
            int slot = atomicAdd(&cur[b], 1);  // LDS atomic; runs contiguous per bucket
            staging[(size_t)b * CAP + slot] = ((unsigned)src[e] << 8) | (unsigned)(d & 255);
        }
    }
}

// One block per bucket. In-block scan of all bucket counts; then local
// deg/scan/cursor in LDS; emit rp, col, dinv.
__global__ __launch_bounds__(256) void p2_csr(const unsigned* __restrict__ staging,
                                              const int* __restrict__ bucketCursor,
                                              int* __restrict__ rp, int* __restrict__ col,
                                              float* __restrict__ dinv, int N, int E, int NB) {
    __shared__ int sb[NBMAX];
    __shared__ int deg[256];
    __shared__ int scn[256];
    __shared__ int cur[256];
    int b = blockIdx.x;
    int tid = threadIdx.x;
    int i1 = tid, i2 = tid + 256;
    sb[i1] = (i1 < NB) ? bucketCursor[i1] : 0;
    sb[i2] = (i2 < NB) ? bucketCursor[i2] : 0;
    deg[tid] = 0;
    __syncthreads();
    for (int off = 1; off < NBMAX; off <<= 1) {  // Hillis-Steele, 2 slots/thread
        int a = (i1 >= off) ? sb[i1 - off] : 0;
        int c = (i2 >= off) ? sb[i2 - off] : 0;
        __syncthreads();
        sb[i1] += a;
        sb[i2] += c;
        __syncthreads();
    }
    int base = (b == 0) ? 0 : sb[b - 1];
    int size = sb[b] - base;
    if (b == 0 && tid == 0) rp[N] = E;
    const unsigned* st = staging + (size_t)b * CAP;
    for (int i = tid; i < size; i += 256) atomicAdd(&deg[st[i] & 255u], 1);
    __syncthreads();
    int g = b * 256 + tid;
    int d = deg[tid];
    if (g < N) dinv[g] = rsqrtf((float)(d + 1));  // +1 self-loop
    scn[tid] = d;
    __syncthreads();
    for (int off = 1; off < 256; off <<= 1) {
        int t = (tid >= off) ? scn[tid - off] : 0;
        __syncthreads();
        scn[tid] += t;
        __syncthreads();
    }
    int excl = scn[tid] - d;
    if (g < N) rp[g] = base + excl;
    cur[tid] = excl;
    __syncthreads();
    for (int i = tid; i < size; i += 256) {
        unsigned pk = st[i];
        int pos = atomicAdd(&cur[pk & 255u], 1);
        col[base + pos] = (int)(pk >> 8);
    }
}

// h1[row] = bf16( (X[row] @ W1) * dinv[row] ); 128-row tile, thread = 4 rows x 8 cols.
__global__ __launch_bounds__(256) void gemm1(const float* __restrict__ X,
                                             const float* __restrict__ W,
                                             const float* __restrict__ dinv,
                                             unsigned short* __restrict__ Hout, int N) {
    constexpr int XS = 65;
    __shared__ float Xs[128 * XS];
    __shared__ float Ws[64 * 64];
    int tid = threadIdx.x;
    int rowBase = blockIdx.x * 128;
    const float4* Wv = (const float4*)W;
    float4* Wsv = (float4*)Ws;
    for (int i = tid; i < 64 * 64 / 4; i += 256) Wsv[i] = Wv[i];
    const float4* Xv = (const float4*)X;
    for (int v = tid; v < 128 * 16; v += 256) {
        int r = v >> 4, j = v & 15;
        int gr = rowBase + r;
        float4 t = make_float4(0.f, 0.f, 0.f, 0.f);
        if (gr < N) t = Xv[(size_t)gr * 16 + j];
        int b = r * XS + j * 4;
        Xs[b] = t.x;
        Xs[b + 1] = t.y;
        Xs[b + 2] = t.z;
        Xs[b + 3] = t.w;
    }
    __syncthreads();
    int cg = tid % 8, rg = tid / 8;
    int c0 = cg * 8, r0 = rg * 4;
    float acc[4][8];
#pragma unroll
    for (int i = 0; i < 4; ++i)
#pragma unroll
        for (int j = 0; j < 8; ++j) acc[i][j] = 0.f;
#pragma unroll 8
    for (int k = 0; k < 64; ++k) {
        float4 w0 = *(const float4*)&Ws[k * 64 + c0];
        float4 w1 = *(const float4*)&Ws[k * 64 + c0 + 4];
        float xr[4];
#pragma unroll
        for (int i = 0; i < 4; ++i) xr[i] = Xs[(r0 + i) * XS + k];
#pragma unroll
        for (int i = 0; i < 4; ++i) {
            acc[i][0] = fmaf(xr[i], w0.x, acc[i][0]);
            acc[i][1] = fmaf(xr[i], w0.y, acc[i][1]);
            acc[i][2] = fmaf(xr[i], w0.z, acc[i][2]);
            acc[i][3] = fmaf(xr[i], w0.w, acc[i][3]);
            acc[i][4] = fmaf(xr[i], w1.x, acc[i][4]);
            acc[i][5] = fmaf(xr[i], w1.y, acc[i][5]);
            acc[i][6] = fmaf(xr[i], w1.z, acc[i][6]);
            acc[i][7] = fmaf(xr[i], w1.w, acc[i][7]);
        }
    }
#pragma unroll
    for (int i = 0; i < 4; ++i) {
        int row = rowBase + r0 + i;
        if (row >= N) continue;
        float dn = dinv[row];
        unsigned pk[4];
#pragma unroll
        for (int j = 0; j < 4; ++j) {
            unsigned lo = f2bf(acc[i][2 * j] * dn);
            unsigned hi = f2bf(acc[i][2 * j + 1] * dn);
            pk[j] = lo | (hi << 16);
        }
        *(uint4*)(Hout + (size_t)row * 64 + c0) = make_uint4(pk[0], pk[1], pk[2], pk[3]);
    }
}

// Fused layer-1 aggregate + layer-2 linear. 16 nodes/block, 16 threads/node =
// 2 edge-subgroups x 8 lanes; pipelined walk; shfl_xor(8) combine.
// Phase B: 16 threads/node x 2 out-ch, conflict-free float2 W2 reads.
__global__ __launch_bounds__(256) void agg1_gemm2(
    const uint4* __restrict__ hs1, const float* __restrict__ dinv, const int* __restrict__ rp,
    const int* __restrict__ col, const float* __restrict__ b1, const float* __restrict__ W2,
    unsigned short* __restrict__ h2, int N) {
    constexpr int RS = 68;
    constexpr int NPB = 16;
    __shared__ float rows[NPB * RS];  // 4352 B
    __shared__ float Ws2[64 * 32];    // 8192 B
    int tid = threadIdx.x;
    const float4* W2v = (const float4*)W2;
    float4* Ws2v = (float4*)Ws2;
    for (int i = tid; i < 64 * 32 / 4; i += 256) Ws2v[i] = W2v[i];

    int r = tid >> 4;   // node slot 0..15
    int t16 = tid & 15;
    int sg = t16 >> 3;  // edge-half
    int q = t16 & 7;    // uint4 quad within row
    int node = blockIdx.x * NPB + r;
    float dn = 0.f;
    float acc[8];
#pragma unroll
    for (int j = 0; j < 8; ++j) acc[j] = 0.f;
    if (node < N) {
        dn = dinv[node];
        if (sg == 0) acc8(acc, hs1[(size_t)node * 8 + q]);  // self-loop (pre-scaled)
        int e0 = rp[node], e1 = rp[node + 1];
        int mid = (e0 + e1 + 1) >> 1;
        walk_pipe<8>(hs1, col, q, sg ? mid : e0, sg ? e1 : mid, acc);
    }
#pragma unroll
    for (int j = 0; j < 8; ++j) acc[j] += __shfl_xor(acc[j], 8, 64);
    if (node < N && sg == 0) {
        const float4* bv = (const float4*)b1;
        float4 bb0 = bv[q * 2], bb1 = bv[q * 2 + 1];
        float* myrow = &rows[r * RS + q * 8];
        *(float4*)myrow =
            make_float4(fmaxf(fmaf(acc[0], dn, bb0.x), 0.f), fmaxf(fmaf(acc[1], dn, bb0.y), 0.f),
                        fmaxf(fmaf(acc[2], dn, bb0.z), 0.f), fmaxf(fmaf(acc[3], dn, bb0.w), 0.f));
        *(float4*)(myrow + 4) =
            make_float4(fmaxf(fmaf(acc[4], dn, bb1.x), 0.f), fmaxf(fmaf(acc[5], dn, bb1.y), 0.f),
                        fmaxf(fmaf(acc[6], dn, bb1.z), 0.f), fmaxf(fmaf(acc[7], dn, bb1.w), 0.f));
    }
    __syncthreads();

    // Phase B: h2[node, c0:c0+2] = bf16( (rows[node] @ W2[:, c0:c0+2]) * dn )
    if (node >= N) return;
    int c0 = t16 * 2;
    float a0 = 0.f, a1 = 0.f;
    const float* row = &rows[r * RS];
#pragma unroll
    for (int k4 = 0; k4 < 16; ++k4) {
        float4 xq = *(const float4*)&row[k4 * 4];
#pragma unroll
        for (int kk = 0; kk < 4; ++kk) {
            float xv = (&xq.x)[kk];
            float2 w = *(const float2*)&Ws2[(k4 * 4 + kk) * 32 + c0];
            a0 = fmaf(xv, w.x, a0);
            a1 = fmaf(xv, w.y, a1);
        }
    }
    unsigned pk = (unsigned)f2bf(a0 * dn) | ((unsigned)f2bf(a1 * dn) << 16);
    *(unsigned*)(h2 + (size_t)node * 32 + c0) = pk;
}

// Layer-2 aggregate: bf16 rows (32 ch). 8 threads/node = 2 edge-subgroups x 4
// lanes; pipelined walk; shfl_xor(4) combine. No LDS, no sync.
__global__ __launch_bounds__(256) void agg2(const uint4* __restrict__ hs2,
                                            const float* __restrict__ dinv,
                                            const int* __restrict__ rp,
                                            const int* __restrict__ col,
                                            const float* __restrict__ bias,
                                            float* __restrict__ out, int N) {
    int tid = blockIdx.x * blockDim.x + threadIdx.x;
    int node = tid >> 3;
    int t8 = tid & 7;
    int sg = t8 >> 2, q = t8 & 3;
    if (node >= N) return;
    float acc[8];
#pragma unroll
    for (int j = 0; j < 8; ++j) acc[j] = 0.f;
    if (sg == 0) acc8(acc, hs2[(size_t)node * 4 + q]);  // self-loop (pre-scaled)
    int e0 = rp[node], e1 = rp[node + 1];
    int mid = (e0 + e1 + 1) >> 1;
    walk_pipe<4>(hs2, col, q, sg ? mid : e0, sg ? e1 : mid, acc);
#pragma unroll
    for (int j = 0; j < 8; ++j) acc[j] += __shfl_xor(acc[j], 4, 64);
    if (sg) return;
    float dn = dinv[node];
    const float4* bv = (const float4*)bias;
    float4 b0 = bv[q * 2], b1 = bv[q * 2 + 1];
    float4* ov = (float4*)(out + (size_t)node * 32 + q * 8);
    ov[0] = make_float4(fmaf(acc[0], dn, b0.x), fmaf(acc[1], dn, b0.y), fmaf(acc[2], dn, b0.z),
                        fmaf(acc[3], dn, b0.w));
    ov[1] = make_float4(fmaf(acc[4], dn, b1.x), fmaf(acc[5], dn, b1.y), fmaf(acc[6], dn, b1.z),
                        fmaf(acc[7], dn, b1.w));
}

extern "C" void kernel_launch(void* const* d_in, const int* in_sizes, int n_in,
                              void* d_out, int out_size, void* d_ws, size_t ws_size,
                              hipStream_t stream) {
    const float* x = (const float*)d_in[0];
    const int* ei = (const int*)d_in[1];  // int64 in reference -> int32 from harness
    const float* W1 = (const float*)d_in[3];
    const float* b1 = (const float*)d_in[4];
    const float* W2 = (const float*)d_in[5];
    const float* b2 = (const float*)d_in[6];

    constexpr int CIN = 64, CHID = 64;
    const int N = in_sizes[0] / CIN;
    const int E = in_sizes[1] / 2;
    const int* src = ei;
    const int* dst = ei + E;
    const int NB = (N + 255) >> 8;  // must be <= NBMAX

    char* p = (char*)d_ws;
    auto carve = [&](size_t bytes) -> void* {
        void* q = (void*)p;
        p += (bytes + 255) & ~(size_t)255;
        return q;
    };
    int* bucketCursor = (int*)carve((size_t)NB * 4);
    int* rp = (int*)carve((size_t)(N + 1) * 4);
    int* col = (int*)carve((size_t)E * 4);
    float* dinv = (float*)carve((size_t)N * 4);
    unsigned* staging = (unsigned*)carve((size_t)NB * CAP * 4);         // 12.8 MB
    unsigned short* h1 = (unsigned short*)carve((size_t)N * CHID * 2);  // bf16
    unsigned short* h2 = (unsigned short*)staging;  // staging dead after p2_csr

    hipMemsetAsync(bucketCursor, 0, (size_t)NB * 4, stream);
    p1_bin<<<(E + 4095) / 4096, 256, 0, stream>>>(src, dst, bucketCursor, staging, E, NB);
    p2_csr<<<NB, 256, 0, stream>>>(staging, bucketCursor, rp, col, dinv, N, E, NB);

    gemm1<<<(N + 127) / 128, 256, 0, stream>>>(x, W1, dinv, h1, N);
    agg1_gemm2<<<(N + 15) / 16, 256, 0, stream>>>((const uint4*)h1, dinv, rp, col, b1, W2, h2, N);
    agg2<<<((size_t)N * 8 + 255) / 256, 256, 0, stream>>>((const uint4*)h2, dinv, rp, col, b2,
                                                          (float*)d_out, N);
}

// Round 10
// 221.821 us; speedup vs baseline: 1.0174x; 1.0174x over previous
//
#include <hip/hip_runtime.h>

// GCN 2-layer encoder on gfx950.
// R10: algebraic refactor — aggregate pre-scaled bf16 x (xs = x*dinv), then
// per-node MLP (W1+relu+W2) inside the gather kernel's phase B (idle VALU).
// Deletes gemm1; xs cast folded into p2_csr. Walk = R8's 4-batch (28 VGPR,
// best-measured occupancy; R7 balance / R9 pipeline both lost to occupancy).
// Pipeline: memset(1.5KB) -> p1_bin -> p2_csr(+dinv+xs) -> agg_mlp -> agg2.

constexpr int CAP = 8192;   // per-bucket staging cap; E/NB ~ 4092
constexpr int NBMAX = 512;  // NB = 391 for N = 100000 (must be <= 512)

__device__ inline unsigned short f2bf(float f) {  // RNE f32->bf16 (finite inputs)
    unsigned u = __float_as_uint(f);
    u += 0x7fff + ((u >> 16) & 1);
    return (unsigned short)(u >> 16);
}
__device__ inline float bflo(unsigned u) { return __uint_as_float(u << 16); }
__device__ inline float bfhi(unsigned u) { return __uint_as_float(u & 0xffff0000u); }

__device__ inline void acc8(float* acc, uint4 u) {
    acc[0] += bflo(u.x); acc[1] += bfhi(u.x);
    acc[2] += bflo(u.y); acc[3] += bfhi(u.y);
    acc[4] += bflo(u.z); acc[5] += bfhi(u.z);
    acc[6] += bflo(u.w); acc[7] += bfhi(u.w);
}

// R8's 4-batch walk: 4 independent gathers in flight, low VGPR.
template <int STRIDE>
__device__ inline void walk4(const uint4* __restrict__ hs, const int* __restrict__ col, int q,
                             int es, int ee, float* acc) {
    int e = es;
    for (; e + 4 <= ee; e += 4) {
        int s0 = col[e], s1 = col[e + 1], s2 = col[e + 2], s3 = col[e + 3];
        uint4 u0 = hs[(size_t)s0 * STRIDE + q];
        uint4 u1 = hs[(size_t)s1 * STRIDE + q];
        uint4 u2 = hs[(size_t)s2 * STRIDE + q];
        uint4 u3 = hs[(size_t)s3 * STRIDE + q];
        acc8(acc, u0); acc8(acc, u1); acc8(acc, u2); acc8(acc, u3);
    }
    for (; e < ee; ++e) acc8(acc, hs[(size_t)col[e] * STRIDE + q]);
}

__global__ __launch_bounds__(256) void p1_bin(const int* __restrict__ src,
                                              const int* __restrict__ dst,
                                              int* __restrict__ bucketCursor,
                                              unsigned* __restrict__ staging, int E, int NB) {
    __shared__ int cnt[NBMAX];
    __shared__ int cur[NBMAX];
    int tid = threadIdx.x;
    for (int i = tid; i < NB; i += 256) cnt[i] = 0;
    __syncthreads();
    int e0 = blockIdx.x * 4096;
#pragma unroll
    for (int k = 0; k < 16; ++k) {
        int e = e0 + k * 256 + tid;
        if (e < E) atomicAdd(&cnt[dst[e] >> 8], 1);  // LDS atomic
    }
    __syncthreads();
    for (int i = tid; i < NB; i += 256) {
        int c = cnt[i];
        cur[i] = c ? atomicAdd(&bucketCursor[i], c) : 0;  // 1 global atomic/(block,bucket)
    }
    __syncthreads();
#pragma unroll
    for (int k = 0; k < 16; ++k) {
        int e = e0 + k * 256 + tid;
        if (e < E) {
            int d = dst[e];
            int b = d >> 8;
            int slot = atomicAdd(&cur[b], 1);  // LDS atomic; runs contiguous per bucket
            staging[(size_t)b * CAP + slot] = ((unsigned)src[e] << 8) | (unsigned)(d & 255);
        }
    }
}

// One block per bucket. In-block scan of bucket counts; local deg/scan/cursor
// in LDS; emit rp, col, dinv, AND xs = bf16(x * dinv) for this bucket's rows.
__global__ __launch_bounds__(256) void p2_csr(const unsigned* __restrict__ staging,
                                              const int* __restrict__ bucketCursor,
                                              const float* __restrict__ x,
                                              int* __restrict__ rp, int* __restrict__ col,
                                              float* __restrict__ dinv,
                                              unsigned short* __restrict__ xs,
                                              int N, int E, int NB) {
    __shared__ int sb[NBMAX];
    __shared__ int deg[256];
    __shared__ int scn[256];
    __shared__ int cur[256];
    __shared__ float dinvs[256];
    int b = blockIdx.x;
    int tid = threadIdx.x;
    int i1 = tid, i2 = tid + 256;
    sb[i1] = (i1 < NB) ? bucketCursor[i1] : 0;
    sb[i2] = (i2 < NB) ? bucketCursor[i2] : 0;
    deg[tid] = 0;
    __syncthreads();
    for (int off = 1; off < NBMAX; off <<= 1) {  // Hillis-Steele, 2 slots/thread
        int a = (i1 >= off) ? sb[i1 - off] : 0;
        int c = (i2 >= off) ? sb[i2 - off] : 0;
        __syncthreads();
        sb[i1] += a;
        sb[i2] += c;
        __syncthreads();
    }
    int base = (b == 0) ? 0 : sb[b - 1];
    int size = sb[b] - base;
    if (b == 0 && tid == 0) rp[N] = E;
    const unsigned* st = staging + (size_t)b * CAP;
    for (int i = tid; i < size; i += 256) atomicAdd(&deg[st[i] & 255u], 1);
    __syncthreads();
    int g = b * 256 + tid;
    int d = deg[tid];
    float dn = rsqrtf((float)(d + 1));  // +1 self-loop
    dinvs[tid] = dn;
    if (g < N) dinv[g] = dn;
    scn[tid] = d;
    __syncthreads();
    for (int off = 1; off < 256; off <<= 1) {
        int t = (tid >= off) ? scn[tid - off] : 0;
        __syncthreads();
        scn[tid] += t;
        __syncthreads();
    }
    int excl = scn[tid] - d;
    if (g < N) rp[g] = base + excl;
    cur[tid] = excl;
    __syncthreads();
    for (int i = tid; i < size; i += 256) {
        unsigned pk = st[i];
        int pos = atomicAdd(&cur[pk & 255u], 1);
        col[base + pos] = (int)(pk >> 8);
    }
    // xs rows for this bucket: coalesced float4 read, scale, pack bf16x4.
    const float4* Xv = (const float4*)x;
    uint2* xsv = (uint2*)xs;
    int rowBase = b * 256;
    for (int v = tid; v < 256 * 16; v += 256) {
        int r = v >> 4, j = v & 15;
        int gr = rowBase + r;
        if (gr < N) {
            float4 t = Xv[(size_t)gr * 16 + j];
            float s = dinvs[r];
            uint2 pk;
            pk.x = (unsigned)f2bf(t.x * s) | ((unsigned)f2bf(t.y * s) << 16);
            pk.y = (unsigned)f2bf(t.z * s) | ((unsigned)f2bf(t.w * s) << 16);
            xsv[(size_t)gr * 16 + j] = pk;
        }
    }
}

// Fused layer-1 aggregate + 2-layer MLP. 16 nodes/block, 16 threads/node =
// 2 edge-subgroups x 8 lanes (xs rows 128B bf16); shfl_xor(8) combine.
// Phase B: a = relu((dn*aggx) @ W1 + b1); h2 = bf16((a @ W2) * dn).
__global__ __launch_bounds__(256) void agg_mlp(
    const uint4* __restrict__ xs, const float* __restrict__ dinv, const int* __restrict__ rp,
    const int* __restrict__ col, const float* __restrict__ b1, const float* __restrict__ W1,
    const float* __restrict__ W2, unsigned short* __restrict__ h2, int N) {
    constexpr int RS = 68;
    constexpr int NPB = 16;
    __shared__ float rows[NPB * RS];  // 4352 B
    __shared__ float W1s[64 * 64];    // 16384 B
    __shared__ float W2s[64 * 32];    // 8192 B
    int tid = threadIdx.x;
    {
        const float4* a = (const float4*)W1;
        float4* d = (float4*)W1s;
        for (int i = tid; i < 64 * 64 / 4; i += 256) d[i] = a[i];
        const float4* a2 = (const float4*)W2;
        float4* d2 = (float4*)W2s;
        for (int i = tid; i < 64 * 32 / 4; i += 256) d2[i] = a2[i];
    }

    int r = tid >> 4;   // node slot 0..15
    int t16 = tid & 15;
    int sg = t16 >> 3;  // edge-half
    int q = t16 & 7;    // uint4 quad within row
    int node = blockIdx.x * NPB + r;
    float dn = 0.f;
    float acc[8];
#pragma unroll
    for (int j = 0; j < 8; ++j) acc[j] = 0.f;
    if (node < N) {
        dn = dinv[node];
        if (sg == 0) acc8(acc, xs[(size_t)node * 8 + q]);  // self-loop (pre-scaled)
        int e0 = rp[node], e1 = rp[node + 1];
        int mid = (e0 + e1 + 1) >> 1;
        walk4<8>(xs, col, q, sg ? mid : e0, sg ? e1 : mid, acc);
    }
#pragma unroll
    for (int j = 0; j < 8; ++j) acc[j] += __shfl_xor(acc[j], 8, 64);
    if (node < N && sg == 0) {
        float* myrow = &rows[r * RS + q * 8];
        *(float4*)myrow = make_float4(acc[0] * dn, acc[1] * dn, acc[2] * dn, acc[3] * dn);
        *(float4*)(myrow + 4) = make_float4(acc[4] * dn, acc[5] * dn, acc[6] * dn, acc[7] * dn);
    }
    __syncthreads();

    if (node >= N) return;
    // Phase B1: a1[c0..c0+3] = relu( rows[node] @ W1[:,c0..3] + b1 )
    int c0 = t16 * 4;
    float a1[4] = {0.f, 0.f, 0.f, 0.f};
    const float* row = &rows[r * RS];
#pragma unroll 16
    for (int k = 0; k < 64; ++k) {
        float xv = row[k];
        float4 w = *(const float4*)&W1s[k * 64 + c0];
        a1[0] = fmaf(xv, w.x, a1[0]);
        a1[1] = fmaf(xv, w.y, a1[1]);
        a1[2] = fmaf(xv, w.z, a1[2]);
        a1[3] = fmaf(xv, w.w, a1[3]);
    }
    float4 bb = *(const float4*)&b1[c0];
    a1[0] = fmaxf(a1[0] + bb.x, 0.f);
    a1[1] = fmaxf(a1[1] + bb.y, 0.f);
    a1[2] = fmaxf(a1[2] + bb.z, 0.f);
    a1[3] = fmaxf(a1[3] + bb.w, 0.f);
    __syncthreads();  // everyone done reading rows
    *(float4*)&rows[r * RS + c0] = make_float4(a1[0], a1[1], a1[2], a1[3]);
    __syncthreads();

    // Phase B2: h2[node, c2..c2+1] = bf16( (rows[node] @ W2[:,c2..1]) * dn )
    int c2 = t16 * 2;
    float h0 = 0.f, h1v = 0.f;
#pragma unroll 16
    for (int k = 0; k < 64; ++k) {
        float av = row[k];
        float2 w = *(const float2*)&W2s[k * 32 + c2];
        h0 = fmaf(av, w.x, h0);
        h1v = fmaf(av, w.y, h1v);
    }
    unsigned pk = (unsigned)f2bf(h0 * dn) | ((unsigned)f2bf(h1v * dn) << 16);
    *(unsigned*)(h2 + (size_t)node * 32 + c2) = pk;
}

// Layer-2 aggregate: bf16 rows (32 ch). 8 threads/node = 2 edge-subgroups x 4
// lanes; 4-batch walk; shfl_xor(4) combine. No LDS, no sync.
__global__ __launch_bounds__(256) void agg2(const uint4* __restrict__ hs2,
                                            const float* __restrict__ dinv,
                                            const int* __restrict__ rp,
                                            const int* __restrict__ col,
                                            const float* __restrict__ bias,
                                            float* __restrict__ out, int N) {
    int tid = blockIdx.x * blockDim.x + threadIdx.x;
    int node = tid >> 3;
    int t8 = tid & 7;
    int sg = t8 >> 2, q = t8 & 3;
    if (node >= N) return;
    float acc[8];
#pragma unroll
    for (int j = 0; j < 8; ++j) acc[j] = 0.f;
    if (sg == 0) acc8(acc, hs2[(size_t)node * 4 + q]);  // self-loop (pre-scaled)
    int e0 = rp[node], e1 = rp[node + 1];
    int mid = (e0 + e1 + 1) >> 1;
    walk4<4>(hs2, col, q, sg ? mid : e0, sg ? e1 : mid, acc);
#pragma unroll
    for (int j = 0; j < 8; ++j) acc[j] += __shfl_xor(acc[j], 4, 64);
    if (sg) return;
    float dn = dinv[node];
    const float4* bv = (const float4*)bias;
    float4 b0 = bv[q * 2], b1 = bv[q * 2 + 1];
    float4* ov = (float4*)(out + (size_t)node * 32 + q * 8);
    ov[0] = make_float4(fmaf(acc[0], dn, b0.x), fmaf(acc[1], dn, b0.y), fmaf(acc[2], dn, b0.z),
                        fmaf(acc[3], dn, b0.w));
    ov[1] = make_float4(fmaf(acc[4], dn, b1.x), fmaf(acc[5], dn, b1.y), fmaf(acc[6], dn, b1.z),
                        fmaf(acc[7], dn, b1.w));
}

extern "C" void kernel_launch(void* const* d_in, const int* in_sizes, int n_in,
                              void* d_out, int out_size, void* d_ws, size_t ws_size,
                              hipStream_t stream) {
    const float* x = (const float*)d_in[0];
    const int* ei = (const int*)d_in[1];  // int64 in reference -> int32 from harness
    const float* W1 = (const float*)d_in[3];
    const float* b1 = (const float*)d_in[4];
    const float* W2 = (const float*)d_in[5];
    const float* b2 = (const float*)d_in[6];

    constexpr int CIN = 64;
    const int N = in_sizes[0] / CIN;
    const int E = in_sizes[1] / 2;
    const int* src = ei;
    const int* dst = ei + E;
    const int NB = (N + 255) >> 8;  // must be <= NBMAX

    char* p = (char*)d_ws;
    auto carve = [&](size_t bytes) -> void* {
        void* q = (void*)p;
        p += (bytes + 255) & ~(size_t)255;
        return q;
    };
    int* bucketCursor = (int*)carve((size_t)NB * 4);
    int* rp = (int*)carve((size_t)(N + 1) * 4);
    int* col = (int*)carve((size_t)E * 4);
    float* dinv = (float*)carve((size_t)N * 4);
    unsigned* staging = (unsigned*)carve((size_t)NB * CAP * 4);        // 12.8 MB
    unsigned short* xs = (unsigned short*)carve((size_t)N * CIN * 2);  // bf16 x*dinv
    unsigned short* h2 = (unsigned short*)staging;  // staging dead after p2_csr

    hipMemsetAsync(bucketCursor, 0, (size_t)NB * 4, stream);
    p1_bin<<<(E + 4095) / 4096, 256, 0, stream>>>(src, dst, bucketCursor, staging, E, NB);
    p2_csr<<<NB, 256, 0, stream>>>(staging, bucketCursor, x, rp, col, dinv, xs, N, E, NB);

    agg_mlp<<<(N + 15) / 16, 256, 0, stream>>>((const uint4*)xs, dinv, rp, col, b1, W1, W2, h2,
                                               N);
    agg2<<<((size_t)N * 8 + 255) / 256, 256, 0, stream>>>((const uint4*)h2, dinv, rp, col, b2,
                                                          (float*)d_out, N);
}